// Round 1
// baseline (7834.309 us; speedup 1.0000x reference)
//
#include <hip/hip_runtime.h>
#include <hip/hip_bf16.h>
#include <cfloat>

#define B_ 2
#define S_ 2048
#define D_ 2048
#define H_ 16
#define KV_ 4
#define HD_ 128
#define R_ 4
#define MLP_ 8192
#define N_ (B_*S_)

// ---------------- mix + RMS (and plain RMS) ----------------
template<bool MIX>
__global__ __launch_bounds__(256) void rms_kernel(
    const float* __restrict__ x, const float* __restrict__ x0,
    const float* __restrict__ rm, float* __restrict__ xm_out,
    float* __restrict__ h_out)
{
    int n = blockIdx.x;
    int tid = threadIdx.x;
    const float4* xr = (const float4*)(x + (size_t)n * D_);
    float4 v[2];
    float ss = 0.f;
#pragma unroll
    for (int i = 0; i < 2; i++) {
        int c = tid + i * 256;
        float4 a = xr[c];
        if (MIX) {
            const float4* x0r = (const float4*)(x0 + (size_t)n * D_);
            const float4* rma = (const float4*)rm;
            const float4* rmb = (const float4*)(rm + D_);
            float4 b = x0r[c];
            float4 ra = rma[c], rb = rmb[c];
            a.x = ra.x*a.x + rb.x*b.x;
            a.y = ra.y*a.y + rb.y*b.y;
            a.z = ra.z*a.z + rb.z*b.z;
            a.w = ra.w*a.w + rb.w*b.w;
            ((float4*)(xm_out + (size_t)n * D_))[c] = a;
        }
        v[i] = a;
        ss += a.x*a.x + a.y*a.y + a.z*a.z + a.w*a.w;
    }
#pragma unroll
    for (int off = 32; off; off >>= 1) ss += __shfl_xor(ss, off);
    __shared__ float red[4];
    if ((tid & 63) == 0) red[tid >> 6] = ss;
    __syncthreads();
    float tot = red[0] + red[1] + red[2] + red[3];
    float r = rsqrtf(tot * (1.f / (float)D_) + FLT_EPSILON);
    float4* ho = (float4*)(h_out + (size_t)n * D_);
#pragma unroll
    for (int i = 0; i < 2; i++) {
        int c = tid + i * 256;
        float4 a = v[i];
        a.x *= r; a.y *= r; a.z *= r; a.w *= r;
        ho[c] = a;
    }
}

// ---------------- generic fp32 GEMM: C[n,m] = sum_k A[n,k]*Bw[m,k] ----------------
// EPI 0: C = acc
// EPI 1: C = acc + src[n,m]                       (v-proj + v_embed -> v_resid)
// EPI 2: C = src[n,m] + svec[m]*acc               (out-proj / down-proj residual)
// EPI 3: t = acc>=0 ? acc : 0.5*acc; C = t*t      (MLP activation)
template<int EPI>
__global__ __launch_bounds__(256) void gemm_f32(
    const float* __restrict__ A, const float* __restrict__ Bw,
    float* __restrict__ C, int M, int Kd,
    const float* __restrict__ src, const float* __restrict__ svec)
{
    __shared__ float As[8][128];
    __shared__ float Bs[8][128];
    int tid = threadIdx.x;
    int bm = blockIdx.y * 128, bn = blockIdx.x * 128;
    int lr = tid >> 1;
    int lc = (tid & 1) * 4;
    const float* Ald = A  + (size_t)(bm + lr) * Kd + lc;
    const float* Bld = Bw + (size_t)(bn + lr) * Kd + lc;
    int tx = tid & 15, ty = tid >> 4;
    float acc[8][8] = {};
    for (int k0 = 0; k0 < Kd; k0 += 8) {
        float4 av = *(const float4*)(Ald + k0);
        float4 bv = *(const float4*)(Bld + k0);
        __syncthreads();
        As[lc+0][lr] = av.x; As[lc+1][lr] = av.y; As[lc+2][lr] = av.z; As[lc+3][lr] = av.w;
        Bs[lc+0][lr] = bv.x; Bs[lc+1][lr] = bv.y; Bs[lc+2][lr] = bv.z; Bs[lc+3][lr] = bv.w;
        __syncthreads();
#pragma unroll
        for (int kk = 0; kk < 8; kk++) {
            float a[8], b[8];
            *(float4*)&a[0] = *(float4*)&As[kk][ty*8];
            *(float4*)&a[4] = *(float4*)&As[kk][ty*8+4];
            *(float4*)&b[0] = *(float4*)&Bs[kk][tx*8];
            *(float4*)&b[4] = *(float4*)&Bs[kk][tx*8+4];
#pragma unroll
            for (int i = 0; i < 8; i++)
#pragma unroll
                for (int j = 0; j < 8; j++)
                    acc[i][j] += a[i] * b[j];
        }
    }
#pragma unroll
    for (int i = 0; i < 8; i++) {
        size_t off = (size_t)(bm + ty*8 + i) * M + bn + tx*8;
#pragma unroll
        for (int j = 0; j < 8; j++) {
            float vv = acc[i][j];
            if (EPI == 1) vv += src[off + j];
            else if (EPI == 2) vv = src[off + j] + svec[bn + tx*8 + j] * vv;
            else if (EPI == 3) { float t = vv >= 0.f ? vv : 0.5f*vv; vv = t*t; }
            C[off + j] = vv;
        }
    }
}

// ---------------- v mixing: vm = l0*v0 + l1*v_resid ----------------
__global__ __launch_bounds__(256) void vmix_kernel(
    const float* __restrict__ vres, const float* __restrict__ v0,
    const float* __restrict__ lam, float* __restrict__ vm)
{
    int i = blockIdx.x * 256 + threadIdx.x;
    float l0 = lam[0], l1 = lam[1];
    float4 a = ((const float4*)vres)[i];
    float4 b = ((const float4*)v0)[i];
    float4 o;
    o.x = l0*b.x + l1*a.x;
    o.y = l0*b.y + l1*a.y;
    o.z = l0*b.z + l1*a.z;
    o.w = l0*b.w + l1*a.w;
    ((float4*)vm)[i] = o;
}

// ---------------- per-head RMS + RoPE (+q_gain) ----------------
__global__ __launch_bounds__(128) void ropeqk_kernel(
    float* __restrict__ q, float* __restrict__ k,
    const float* __restrict__ q_gain)
{
    int n = blockIdx.x;
    int head = blockIdx.y;    // 0..15 = q heads, 16..19 = k heads
    int tid = threadIdx.x;    // 0..127
    bool isq = head < H_;
    float* vec = isq ? (q + (size_t)n * D_ + head * HD_)
                     : (k + (size_t)n * (KV_*HD_) + (head - H_) * HD_);
    float v = vec[tid];
    float ss = v * v;
#pragma unroll
    for (int off = 32; off; off >>= 1) ss += __shfl_xor(ss, off);
    __shared__ float red[2];
    __shared__ float sh[HD_];
    if ((tid & 63) == 0) red[tid >> 6] = ss;
    __syncthreads();
    float tot = red[0] + red[1];
    float r = rsqrtf(tot * (1.f / (float)HD_) + FLT_EPSILON);
    float xn = v * r;
    sh[tid] = xn;
    __syncthreads();
    int s = n & (S_ - 1);
    int i = (tid < 64) ? tid : tid - 64;
    // base = 10000 * (S/TRAIN)^(d/(d-2)) = 10000 * 2^(128/126); log2(base):
    const float L2B = 14.303585395422465f;
    float invf = exp2f(-(float)i * (L2B / 64.f));
    float fr = (float)s * invf;
    float c = cosf(fr), sn = sinf(fr);
    float out;
    if (tid < 64) out =  xn * c + sh[tid + 64] * sn;
    else          out = -sh[tid - 64] * sn + xn * c;
    if (isq) out *= q_gain[head];
    vec[tid] = out;
}

// ---------------- flash attention (fp32, online softmax), GQA ----------------
__global__ __launch_bounds__(256) void attn_kernel(
    const float* __restrict__ Qg, const float* __restrict__ Kg,
    const float* __restrict__ Vg, float* __restrict__ Y)
{
    const int b = blockIdx.z, h = blockIdx.y;
    const int kv = h >> 2;
    const int s0 = blockIdx.x * 32;
    const int tid = threadIdx.x;
    __shared__ float Qs[32][132];
    __shared__ float Ks[32][132];
    __shared__ float Vs[32][132];
    __shared__ float Sc[32][33];
    __shared__ float rowm[32], rowl[32], rowa[32];
#pragma unroll
    for (int i = 0; i < 4; i++) {
        int u = tid + i * 256;
        int r = u >> 5, c = (u & 31) * 4;
        *(float4*)&Qs[r][c] = *(const float4*)&Qg[(size_t)(b*S_ + s0 + r)*D_ + h*HD_ + c];
    }
    if (tid < 32) { rowm[tid] = -1e30f; rowl[tid] = 0.f; }
    float o[16];
#pragma unroll
    for (int i = 0; i < 16; i++) o[i] = 0.f;
    const int oq = tid >> 3, od = (tid & 7) * 16;
    const int tx = tid & 15, ty = tid >> 4;
    const int ntiles = s0 / 32 + 1;
    __syncthreads();
    for (int t = 0; t < ntiles; t++) {
        int k0 = t * 32;
#pragma unroll
        for (int i = 0; i < 4; i++) {
            int u = tid + i * 256;
            int r = u >> 5, c = (u & 31) * 4;
            size_t g = (size_t)(b*S_ + k0 + r) * (KV_*HD_) + kv*HD_ + c;
            *(float4*)&Ks[r][c] = *(const float4*)&Kg[g];
            *(float4*)&Vs[r][c] = *(const float4*)&Vg[g];
        }
        __syncthreads();
        int q0 = ty*2, q1 = q0+1, j0 = tx*2, j1 = j0+1;
        float s00=0.f, s01=0.f, s10=0.f, s11=0.f;
#pragma unroll
        for (int d = 0; d < 128; d += 4) {
            float4 a0 = *(float4*)&Qs[q0][d];
            float4 a1 = *(float4*)&Qs[q1][d];
            float4 b0 = *(float4*)&Ks[j0][d];
            float4 b1 = *(float4*)&Ks[j1][d];
            s00 += a0.x*b0.x + a0.y*b0.y + a0.z*b0.z + a0.w*b0.w;
            s01 += a0.x*b1.x + a0.y*b1.y + a0.z*b1.z + a0.w*b1.w;
            s10 += a1.x*b0.x + a1.y*b0.y + a1.z*b0.z + a1.w*b0.w;
            s11 += a1.x*b1.x + a1.y*b1.y + a1.z*b1.z + a1.w*b1.w;
        }
        const float scl = 0.08838834764831845f;
        Sc[q0][j0] = (k0+j0 <= s0+q0) ? s00*scl : -1e30f;
        Sc[q0][j1] = (k0+j1 <= s0+q0) ? s01*scl : -1e30f;
        Sc[q1][j0] = (k0+j0 <= s0+q1) ? s10*scl : -1e30f;
        Sc[q1][j1] = (k0+j1 <= s0+q1) ? s11*scl : -1e30f;
        __syncthreads();
        if (tid < 32) {
            float mold = rowm[tid];
            float mx = mold;
            for (int j = 0; j < 32; j++) mx = fmaxf(mx, Sc[tid][j]);
            float alpha = __expf(mold - mx);
            float ssum = 0.f;
            for (int j = 0; j < 32; j++) {
                float p = __expf(Sc[tid][j] - mx);
                Sc[tid][j] = p;
                ssum += p;
            }
            rowl[tid] = rowl[tid]*alpha + ssum;
            rowm[tid] = mx;
            rowa[tid] = alpha;
        }
        __syncthreads();
        float alpha = rowa[oq];
#pragma unroll
        for (int i = 0; i < 16; i++) o[i] *= alpha;
        for (int j = 0; j < 32; j++) {
            float p = Sc[oq][j];
#pragma unroll
            for (int i = 0; i < 16; i += 4) {
                float4 vv = *(float4*)&Vs[j][od + i];
                o[i]   += p*vv.x;
                o[i+1] += p*vv.y;
                o[i+2] += p*vv.z;
                o[i+3] += p*vv.w;
            }
        }
        __syncthreads();
    }
    float invl = 1.f / rowl[oq];
    size_t base = (size_t)(b*S_ + s0 + oq)*D_ + h*HD_ + od;
#pragma unroll
    for (int i = 0; i < 16; i += 4) {
        float4 w;
        w.x = o[i]*invl; w.y = o[i+1]*invl; w.z = o[i+2]*invl; w.w = o[i+3]*invl;
        *(float4*)&Y[base + i] = w;
    }
}

// ---------------- v-hat projection + sigmoid gate (per token) ----------------
__global__ __launch_bounds__(256) void postproc_kernel(
    const float* __restrict__ h, const float* __restrict__ vmix,
    const float* __restrict__ gw, const float* __restrict__ gb,
    float* __restrict__ y)
{
    int n = blockIdx.x;
    int tid = threadIdx.x;
    int wave = tid >> 6, lane = tid & 63;   // wave = kv head
    const float* hrow = h + (size_t)n * D_;
    float acc[4] = {0.f, 0.f, 0.f, 0.f};
    for (int d = lane; d < D_; d += 64) {
        float hv = hrow[d];
#pragma unroll
        for (int r = 0; r < 4; r++)
            acc[r] += hv * gw[(size_t)(wave*4 + r) * D_ + d];
    }
#pragma unroll
    for (int off = 32; off; off >>= 1)
#pragma unroll
        for (int r = 0; r < 4; r++) acc[r] += __shfl_xor(acc[r], off);
    float gate[4];
#pragma unroll
    for (int r = 0; r < 4; r++)
        gate[r] = 1.f / (1.f + __expf(-(acc[r] + gb[wave*4 + r])));
    const float* vrow = vmix + (size_t)n * (KV_*HD_) + wave * HD_;
    float v0 = vrow[lane], v1 = vrow[lane + 64];
    float ss = v0*v0 + v1*v1;
#pragma unroll
    for (int off = 32; off; off >>= 1) ss += __shfl_xor(ss, off);
    float nrm = fmaxf(sqrtf(ss), 1e-12f);
    float vh0 = v0 / nrm, vh1 = v1 / nrm;
    float* yrow = y + (size_t)n * D_ + wave * (R_ * HD_);
#pragma unroll
    for (int r = 0; r < 4; r++) {
        float y0 = yrow[r*HD_ + lane], y1 = yrow[r*HD_ + lane + 64];
        float dot = y0*vh0 + y1*vh1;
#pragma unroll
        for (int off = 32; off; off >>= 1) dot += __shfl_xor(dot, off);
        yrow[r*HD_ + lane]      = (y0 - dot*vh0) * gate[r];
        yrow[r*HD_ + lane + 64] = (y1 - dot*vh1) * gate[r];
    }
}

extern "C" void kernel_launch(void* const* d_in, const int* in_sizes, int n_in,
                              void* d_out, int out_size, void* d_ws, size_t ws_size,
                              hipStream_t stream) {
    const float* x          = (const float*)d_in[0];
    const float* x0         = (const float*)d_in[1];
    const float* q_w        = (const float*)d_in[2];
    const float* k_w        = (const float*)d_in[3];
    const float* v_w        = (const float*)d_in[4];
    const float* out_w      = (const float*)d_in[5];
    const float* up_w       = (const float*)d_in[6];
    const float* down_w     = (const float*)d_in[7];
    const float* v_embed    = (const float*)d_in[8];
    const float* v0         = (const float*)d_in[9];
    const float* q_gain     = (const float*)d_in[10];
    const float* gate_w     = (const float*)d_in[11];
    const float* gate_b     = (const float*)d_in[12];
    const float* vr_lambda  = (const float*)d_in[13];
    const float* attn_scale = (const float*)d_in[14];
    const float* mlp_scale  = (const float*)d_in[15];
    const float* resid_mix  = (const float*)d_in[16];

    float* out_c  = (float*)d_out;
    float* out_vr = out_c + (size_t)N_ * D_;

    float* ws   = (float*)d_ws;
    float* xm   = ws;                                  // N*D
    float* hbuf = ws + (size_t)N_ * D_;                // N*D
    float* qb   = ws + (size_t)2 * N_ * D_;            // N*D
    float* kb   = ws + (size_t)3 * N_ * D_;            // N*512
    float* vmix = kb + (size_t)N_ * KV_ * HD_;         // N*512
    float* yb   = vmix + (size_t)N_ * KV_ * HD_;       // N*D
    float* act  = ws;                                  // N*MLP (reuses xm/h/q after out-proj)
    float* m2   = ws + (size_t)N_ * MLP_;              // N*D

    // 1. xm = mix(x, x0); h = rms(xm)
    rms_kernel<true><<<N_, 256, 0, stream>>>(x, x0, resid_mix, xm, hbuf);
    // 2. q/k/v projections
    gemm_f32<0><<<dim3(D_/128, N_/128), 256, 0, stream>>>(hbuf, q_w, qb, D_, D_, nullptr, nullptr);
    gemm_f32<0><<<dim3((KV_*HD_)/128, N_/128), 256, 0, stream>>>(hbuf, k_w, kb, KV_*HD_, D_, nullptr, nullptr);
    //    v_resid = h@v_w.T + v_embed  -> written straight to output slot 2
    gemm_f32<1><<<dim3((KV_*HD_)/128, N_/128), 256, 0, stream>>>(hbuf, v_w, out_vr, KV_*HD_, D_, v_embed, nullptr);
    // 3. v = l0*v0 + l1*v_resid
    vmix_kernel<<<(N_*KV_*HD_/4)/256, 256, 0, stream>>>(out_vr, v0, vr_lambda, vmix);
    // 4. per-head rms + rope (+gain on q)
    ropeqk_kernel<<<dim3(N_, H_ + KV_), 128, 0, stream>>>(qb, kb, q_gain);
    // 5. causal GQA attention -> yb
    attn_kernel<<<dim3(S_/32, H_, B_), 256, 0, stream>>>(qb, kb, vmix, yb);
    // 6. v-hat projection + gate (in-place on yb)
    postproc_kernel<<<N_, 256, 0, stream>>>(hbuf, vmix, gate_w, gate_b, yb);
    // 7. c = xm + attn_scale * (yb @ out_w.T)   -> out_c
    gemm_f32<2><<<dim3(D_/128, N_/128), 256, 0, stream>>>(yb, out_w, out_c, D_, D_, xm, attn_scale);
    // 8. m2 = rms(c)
    rms_kernel<false><<<N_, 256, 0, stream>>>(out_c, nullptr, nullptr, nullptr, m2);
    // 9. act = sqrelu(m2 @ up_w.T)
    gemm_f32<3><<<dim3(MLP_/128, N_/128), 256, 0, stream>>>(m2, up_w, act, MLP_, D_, nullptr, nullptr);
    // 10. c += mlp_scale * (act @ down_w.T)
    gemm_f32<2><<<dim3(D_/128, N_/128), 256, 0, stream>>>(act, down_w, out_c, D_, MLP_, out_c, mlp_scale);
}

// Round 2
// 2610.430 us; speedup vs baseline: 3.0012x; 3.0012x over previous
//
#include <hip/hip_runtime.h>
#include <hip/hip_bf16.h>
#include <cfloat>

#define B_ 2
#define S_ 2048
#define D_ 2048
#define H_ 16
#define KV_ 4
#define HD_ 128
#define R_ 4
#define MLP_ 8192
#define N_ (B_*S_)

typedef unsigned short ushort_t;
typedef __bf16 bf16x8 __attribute__((ext_vector_type(8)));
typedef float f32x4 __attribute__((ext_vector_type(4)));

__device__ __forceinline__ float b2f(ushort_t u) {
    unsigned x = ((unsigned)u) << 16;
    return __builtin_bit_cast(float, x);
}
__device__ __forceinline__ ushort_t f2b(float f) {
    unsigned u = __builtin_bit_cast(unsigned, f);
    unsigned r = (u + 0x7fffu + ((u >> 16) & 1u)) >> 16;   // RNE
    return (ushort_t)r;
}
__device__ __forceinline__ float b2f_lo(unsigned v){ return __builtin_bit_cast(float, v << 16); }
__device__ __forceinline__ float b2f_hi(unsigned v){ return __builtin_bit_cast(float, v & 0xffff0000u); }

__device__ __forceinline__ void gload_lds16(const void* g, void* l) {
    __builtin_amdgcn_global_load_lds(
        (__attribute__((address_space(1))) void*)(g),
        (__attribute__((address_space(3))) void*)(l), 16, 0, 0);
}

// ---------------- fp32 -> bf16 conversion ----------------
__global__ __launch_bounds__(256) void f2bf_kernel(const float* __restrict__ in,
                                                   ushort_t* __restrict__ out, int n4)
{
    int i = blockIdx.x * 256 + threadIdx.x;
    if (i < n4) {
        float4 v = ((const float4*)in)[i];
        ushort4 o;
        o.x = f2b(v.x); o.y = f2b(v.y); o.z = f2b(v.z); o.w = f2b(v.w);
        ((ushort4*)out)[i] = o;
    }
}

// ---------------- mix + RMS -> bf16 h (optionally fp32 xm) ----------------
template<bool MIX>
__global__ __launch_bounds__(256) void rms_kernel(
    const float* __restrict__ x, const float* __restrict__ x0,
    const float* __restrict__ rm, float* __restrict__ xm_out,
    ushort_t* __restrict__ h_out)
{
    int n = blockIdx.x;
    int tid = threadIdx.x;
    const float4* xr = (const float4*)(x + (size_t)n * D_);
    float4 v[2];
    float ss = 0.f;
#pragma unroll
    for (int i = 0; i < 2; i++) {
        int c = tid + i * 256;
        float4 a = xr[c];
        if (MIX) {
            const float4* x0r = (const float4*)(x0 + (size_t)n * D_);
            const float4* rma = (const float4*)rm;
            const float4* rmb = (const float4*)(rm + D_);
            float4 b = x0r[c];
            float4 ra = rma[c], rb = rmb[c];
            a.x = ra.x*a.x + rb.x*b.x;
            a.y = ra.y*a.y + rb.y*b.y;
            a.z = ra.z*a.z + rb.z*b.z;
            a.w = ra.w*a.w + rb.w*b.w;
            ((float4*)(xm_out + (size_t)n * D_))[c] = a;
        }
        v[i] = a;
        ss += a.x*a.x + a.y*a.y + a.z*a.z + a.w*a.w;
    }
#pragma unroll
    for (int off = 32; off; off >>= 1) ss += __shfl_xor(ss, off);
    __shared__ float red[4];
    if ((tid & 63) == 0) red[tid >> 6] = ss;
    __syncthreads();
    float tot = red[0] + red[1] + red[2] + red[3];
    float r = rsqrtf(tot * (1.f / (float)D_) + FLT_EPSILON);
    ushort4* ho = (ushort4*)(h_out + (size_t)n * D_);
#pragma unroll
    for (int i = 0; i < 2; i++) {
        int c = tid + i * 256;
        float4 a = v[i];
        ushort4 o;
        o.x = f2b(a.x * r); o.y = f2b(a.y * r); o.z = f2b(a.z * r); o.w = f2b(a.w * r);
        ho[c] = o;
    }
}

// ---------------- bf16 MFMA GEMM: C[n,m] = sum_k A[n,k]*W[m,k] ----------------
// 128x128 tile, BK=32, 4 waves each 64x64 (4x4 of 16x16x32 MFMA).
// EPI 0: C = acc
// EPI 1: C = acc + src[n,m]
// EPI 2: C = src[n,m] + svec[m]*acc
// EPI 3: t = leaky(acc); C = t*t
template<int EPI, typename OutT>
__global__ __launch_bounds__(256) void gemm_bf16(
    const ushort_t* __restrict__ A, const ushort_t* __restrict__ W,
    OutT* __restrict__ C, int M, int Kd,
    const float* __restrict__ src, const float* __restrict__ svec)
{
    __shared__ ushort_t As[128 * 32];
    __shared__ ushort_t Bs[128 * 32];
    const int tid = threadIdx.x;
    const int wid = tid >> 6, lane = tid & 63;
    const int bn = blockIdx.y * 128;      // token rows
    const int bm = blockIdx.x * 128;      // feature cols
    const int wn = (wid >> 1) * 64;       // wave row base in tile
    const int wm = (wid & 1) * 64;        // wave col base in tile

    f32x4 acc[4][4] = {};

    const int lr = lane & 15;             // fragment row
    const int lk = (lane >> 4) * 16;      // fragment k byte offset
    const char* Ab = (const char*)As;
    const char* Bb = (const char*)Bs;

    // staging: chunk u in [0,512): row=u>>2, col-chunk=(u&3)*8 elems; LDS dest wave-uniform
    const int ub0 = wid * 128;

    // prologue loads (k0 = 0)
#pragma unroll
    for (int p = 0; p < 2; p++) {
        int ub = ub0 + p * 64;
        int u = ub + lane;
        gload_lds16(A + (size_t)(bn + (u >> 2)) * Kd + (u & 3) * 8, (char*)As + ub * 16);
        gload_lds16(W + (size_t)(bm + (u >> 2)) * Kd + (u & 3) * 8, (char*)Bs + ub * 16);
    }
    __syncthreads();

    for (int k0 = 0;;) {
        bf16x8 af[4], bfr[4];
#pragma unroll
        for (int i = 0; i < 4; i++)
            af[i] = *(const bf16x8*)(Ab + (wn + i * 16 + lr) * 64 + lk);
#pragma unroll
        for (int j = 0; j < 4; j++)
            bfr[j] = *(const bf16x8*)(Bb + (wm + j * 16 + lr) * 64 + lk);
#pragma unroll
        for (int i = 0; i < 4; i++)
#pragma unroll
            for (int j = 0; j < 4; j++)
                acc[i][j] = __builtin_amdgcn_mfma_f32_16x16x32_bf16(af[i], bfr[j], acc[i][j], 0, 0, 0);

        k0 += 32;
        if (k0 >= Kd) break;
        __syncthreads();
#pragma unroll
        for (int p = 0; p < 2; p++) {
            int ub = ub0 + p * 64;
            int u = ub + lane;
            gload_lds16(A + (size_t)(bn + (u >> 2)) * Kd + k0 + (u & 3) * 8, (char*)As + ub * 16);
            gload_lds16(W + (size_t)(bm + (u >> 2)) * Kd + k0 + (u & 3) * 8, (char*)Bs + ub * 16);
        }
        __syncthreads();
    }

    // epilogue: D row=(lane>>4)*4+reg (token), col=lane&15 (feature)
    const int cr = (lane >> 4) * 4;
    const int ccol = lane & 15;
#pragma unroll
    for (int i = 0; i < 4; i++) {
#pragma unroll
        for (int r = 0; r < 4; r++) {
            size_t rowoff = (size_t)(bn + wn + i * 16 + cr + r) * M;
#pragma unroll
            for (int j = 0; j < 4; j++) {
                int m = bm + wm + j * 16 + ccol;
                size_t off = rowoff + m;
                float v = acc[i][j][r];
                if (EPI == 1) v += src[off];
                else if (EPI == 2) v = src[off] + svec[m] * v;
                else if (EPI == 3) { float t = v >= 0.f ? v : 0.5f * v; v = t * t; }
                if constexpr (sizeof(OutT) == 2) C[off] = (OutT)f2b(v);
                else                             C[off] = v;
            }
        }
    }
}

// ---------------- v mixing: vm(bf16) = l0*v0 + l1*v_resid ----------------
__global__ __launch_bounds__(256) void vmix_kernel(
    const float* __restrict__ vres, const float* __restrict__ v0,
    const float* __restrict__ lam, ushort_t* __restrict__ vm)
{
    int i = blockIdx.x * 256 + threadIdx.x;
    float l0 = lam[0], l1 = lam[1];
    float4 a = ((const float4*)vres)[i];
    float4 b = ((const float4*)v0)[i];
    ushort4 o;
    o.x = f2b(l0*b.x + l1*a.x);
    o.y = f2b(l0*b.y + l1*a.y);
    o.z = f2b(l0*b.z + l1*a.z);
    o.w = f2b(l0*b.w + l1*a.w);
    ((ushort4*)vm)[i] = o;
}

// ---------------- per-head RMS + RoPE (+q_gain), bf16 in/out ----------------
__global__ __launch_bounds__(128) void ropeqk_kernel(
    ushort_t* __restrict__ q, ushort_t* __restrict__ k,
    const float* __restrict__ q_gain)
{
    int n = blockIdx.x;
    int head = blockIdx.y;    // 0..15 = q heads, 16..19 = k heads
    int tid = threadIdx.x;    // 0..127
    bool isq = head < H_;
    ushort_t* vec = isq ? (q + (size_t)n * D_ + head * HD_)
                        : (k + (size_t)n * (KV_*HD_) + (head - H_) * HD_);
    float v = b2f(vec[tid]);
    float ss = v * v;
#pragma unroll
    for (int off = 32; off; off >>= 1) ss += __shfl_xor(ss, off);
    __shared__ float red[2];
    __shared__ float sh[HD_];
    if ((tid & 63) == 0) red[tid >> 6] = ss;
    __syncthreads();
    float tot = red[0] + red[1];
    float r = rsqrtf(tot * (1.f / (float)HD_) + FLT_EPSILON);
    float xn = v * r;
    sh[tid] = xn;
    __syncthreads();
    int s = n & (S_ - 1);
    int i = (tid < 64) ? tid : tid - 64;
    const float L2B = 14.303585395422465f;  // log2(10000 * 2^(128/126))
    float invf = exp2f(-(float)i * (L2B / 64.f));
    float fr = (float)s * invf;
    float c = cosf(fr), sn = sinf(fr);
    float out;
    if (tid < 64) out =  xn * c + sh[tid + 64] * sn;
    else          out = -sh[tid - 64] * sn + xn * c;
    if (isq) out *= q_gain[head];
    vec[tid] = f2b(out);
}

// ---------------- flash attention (fp32 compute, bf16 I/O), GQA ----------------
__global__ __launch_bounds__(256) void attn_kernel(
    const ushort_t* __restrict__ Qg, const ushort_t* __restrict__ Kg,
    const ushort_t* __restrict__ Vg, ushort_t* __restrict__ Y)
{
    const int b = blockIdx.z, h = blockIdx.y;
    const int kv = h >> 2;
    const int s0 = blockIdx.x * 32;
    const int tid = threadIdx.x;
    __shared__ float Qs[32][132];
    __shared__ float Ks[32][132];
    __shared__ float Vs[32][132];
    __shared__ float Sc[32][33];
    __shared__ float rowm[32], rowl[32], rowa[32];
#pragma unroll
    for (int i = 0; i < 2; i++) {
        int u = tid + i * 256;
        int r = u >> 4, c = (u & 15) * 8;
        uint4 raw = *(const uint4*)&Qg[(size_t)(b*S_ + s0 + r)*D_ + h*HD_ + c];
        float* dst = &Qs[r][c];
        dst[0] = b2f_lo(raw.x); dst[1] = b2f_hi(raw.x);
        dst[2] = b2f_lo(raw.y); dst[3] = b2f_hi(raw.y);
        dst[4] = b2f_lo(raw.z); dst[5] = b2f_hi(raw.z);
        dst[6] = b2f_lo(raw.w); dst[7] = b2f_hi(raw.w);
    }
    if (tid < 32) { rowm[tid] = -1e30f; rowl[tid] = 0.f; }
    float o[16];
#pragma unroll
    for (int i = 0; i < 16; i++) o[i] = 0.f;
    const int oq = tid >> 3, od = (tid & 7) * 16;
    const int tx = tid & 15, ty = tid >> 4;
    const int ntiles = s0 / 32 + 1;
    __syncthreads();
    for (int t = 0; t < ntiles; t++) {
        int k0 = t * 32;
#pragma unroll
        for (int i = 0; i < 2; i++) {
            int u = tid + i * 256;
            int r = u >> 4, c = (u & 15) * 8;
            size_t g = (size_t)(b*S_ + k0 + r) * (KV_*HD_) + kv*HD_ + c;
            uint4 rk = *(const uint4*)&Kg[g];
            uint4 rv = *(const uint4*)&Vg[g];
            float* dk = &Ks[r][c];
            dk[0]=b2f_lo(rk.x); dk[1]=b2f_hi(rk.x); dk[2]=b2f_lo(rk.y); dk[3]=b2f_hi(rk.y);
            dk[4]=b2f_lo(rk.z); dk[5]=b2f_hi(rk.z); dk[6]=b2f_lo(rk.w); dk[7]=b2f_hi(rk.w);
            float* dv = &Vs[r][c];
            dv[0]=b2f_lo(rv.x); dv[1]=b2f_hi(rv.x); dv[2]=b2f_lo(rv.y); dv[3]=b2f_hi(rv.y);
            dv[4]=b2f_lo(rv.z); dv[5]=b2f_hi(rv.z); dv[6]=b2f_lo(rv.w); dv[7]=b2f_hi(rv.w);
        }
        __syncthreads();
        int q0 = ty*2, q1 = q0+1, j0 = tx*2, j1 = j0+1;
        float s00=0.f, s01=0.f, s10=0.f, s11=0.f;
#pragma unroll
        for (int d = 0; d < 128; d += 4) {
            float4 a0 = *(float4*)&Qs[q0][d];
            float4 a1 = *(float4*)&Qs[q1][d];
            float4 b0 = *(float4*)&Ks[j0][d];
            float4 b1 = *(float4*)&Ks[j1][d];
            s00 += a0.x*b0.x + a0.y*b0.y + a0.z*b0.z + a0.w*b0.w;
            s01 += a0.x*b1.x + a0.y*b1.y + a0.z*b1.z + a0.w*b1.w;
            s10 += a1.x*b0.x + a1.y*b0.y + a1.z*b0.z + a1.w*b0.w;
            s11 += a1.x*b1.x + a1.y*b1.y + a1.z*b1.z + a1.w*b1.w;
        }
        const float scl = 0.08838834764831845f;
        Sc[q0][j0] = (k0+j0 <= s0+q0) ? s00*scl : -1e30f;
        Sc[q0][j1] = (k0+j1 <= s0+q0) ? s01*scl : -1e30f;
        Sc[q1][j0] = (k0+j0 <= s0+q1) ? s10*scl : -1e30f;
        Sc[q1][j1] = (k0+j1 <= s0+q1) ? s11*scl : -1e30f;
        __syncthreads();
        if (tid < 32) {
            float mold = rowm[tid];
            float mx = mold;
            for (int j = 0; j < 32; j++) mx = fmaxf(mx, Sc[tid][j]);
            float alpha = __expf(mold - mx);
            float ssum = 0.f;
            for (int j = 0; j < 32; j++) {
                float p = __expf(Sc[tid][j] - mx);
                Sc[tid][j] = p;
                ssum += p;
            }
            rowl[tid] = rowl[tid]*alpha + ssum;
            rowm[tid] = mx;
            rowa[tid] = alpha;
        }
        __syncthreads();
        float alpha = rowa[oq];
#pragma unroll
        for (int i = 0; i < 16; i++) o[i] *= alpha;
        for (int j = 0; j < 32; j++) {
            float p = Sc[oq][j];
#pragma unroll
            for (int i = 0; i < 16; i += 4) {
                float4 vv = *(float4*)&Vs[j][od + i];
                o[i]   += p*vv.x;
                o[i+1] += p*vv.y;
                o[i+2] += p*vv.z;
                o[i+3] += p*vv.w;
            }
        }
        __syncthreads();
    }
    float invl = 1.f / rowl[oq];
    size_t base = (size_t)(b*S_ + s0 + oq)*D_ + h*HD_ + od;
#pragma unroll
    for (int i = 0; i < 16; i += 4) {
        ushort4 w;
        w.x = f2b(o[i]*invl); w.y = f2b(o[i+1]*invl);
        w.z = f2b(o[i+2]*invl); w.w = f2b(o[i+3]*invl);
        *(ushort4*)&Y[base + i] = w;
    }
}

// ---------------- v-hat projection + sigmoid gate (bf16 y in-place) ----------------
__global__ __launch_bounds__(256) void postproc_kernel(
    const ushort_t* __restrict__ h, const ushort_t* __restrict__ vmix,
    const float* __restrict__ gw, const float* __restrict__ gb,
    ushort_t* __restrict__ y)
{
    int n = blockIdx.x;
    int tid = threadIdx.x;
    int wave = tid >> 6, lane = tid & 63;   // wave = kv head
    const ushort_t* hrow = h + (size_t)n * D_;
    float acc[4] = {0.f, 0.f, 0.f, 0.f};
    for (int d = lane; d < D_; d += 64) {
        float hv = b2f(hrow[d]);
#pragma unroll
        for (int r = 0; r < 4; r++)
            acc[r] += hv * gw[(size_t)(wave*4 + r) * D_ + d];
    }
#pragma unroll
    for (int off = 32; off; off >>= 1)
#pragma unroll
        for (int r = 0; r < 4; r++) acc[r] += __shfl_xor(acc[r], off);
    float gate[4];
#pragma unroll
    for (int r = 0; r < 4; r++)
        gate[r] = 1.f / (1.f + __expf(-(acc[r] + gb[wave*4 + r])));
    const ushort_t* vrow = vmix + (size_t)n * (KV_*HD_) + wave * HD_;
    float v0 = b2f(vrow[lane]), v1 = b2f(vrow[lane + 64]);
    float ss = v0*v0 + v1*v1;
#pragma unroll
    for (int off = 32; off; off >>= 1) ss += __shfl_xor(ss, off);
    float nrm = fmaxf(sqrtf(ss), 1e-12f);
    float vh0 = v0 / nrm, vh1 = v1 / nrm;
    ushort_t* yrow = y + (size_t)n * D_ + wave * (R_ * HD_);
#pragma unroll
    for (int r = 0; r < 4; r++) {
        float y0 = b2f(yrow[r*HD_ + lane]), y1 = b2f(yrow[r*HD_ + lane + 64]);
        float dot = y0*vh0 + y1*vh1;
#pragma unroll
        for (int off = 32; off; off >>= 1) dot += __shfl_xor(dot, off);
        yrow[r*HD_ + lane]      = f2b((y0 - dot*vh0) * gate[r]);
        yrow[r*HD_ + lane + 64] = f2b((y1 - dot*vh1) * gate[r]);
    }
}

extern "C" void kernel_launch(void* const* d_in, const int* in_sizes, int n_in,
                              void* d_out, int out_size, void* d_ws, size_t ws_size,
                              hipStream_t stream) {
    const float* x          = (const float*)d_in[0];
    const float* x0         = (const float*)d_in[1];
    const float* q_w        = (const float*)d_in[2];
    const float* k_w        = (const float*)d_in[3];
    const float* v_w        = (const float*)d_in[4];
    const float* out_w      = (const float*)d_in[5];
    const float* up_w       = (const float*)d_in[6];
    const float* down_w     = (const float*)d_in[7];
    const float* v_embed    = (const float*)d_in[8];
    const float* v0         = (const float*)d_in[9];
    const float* q_gain     = (const float*)d_in[10];
    const float* gate_w     = (const float*)d_in[11];
    const float* gate_b     = (const float*)d_in[12];
    const float* vr_lambda  = (const float*)d_in[13];
    const float* attn_scale = (const float*)d_in[14];
    const float* mlp_scale  = (const float*)d_in[15];
    const float* resid_mix  = (const float*)d_in[16];

    float* out_c  = (float*)d_out;
    float* out_vr = out_c + (size_t)N_ * D_;

    // phase-aliased workspace (peak 151.0 MB; round-1 proved >=160 MiB usable)
    char* w = (char*)d_ws;
    ushort_t* hb  = (ushort_t*)(w + 0);            // 16.8MB, dead after postproc
    float*    xm  = (float*)   (w + 16777216);     // 33.5MB, dead after out-proj
    ushort_t* qb  = (ushort_t*)(w + 50331648);     // 16.8MB, dead after attn
    ushort_t* kb  = (ushort_t*)(w + 67108864);     //  4.2MB, dead after attn
    ushort_t* vmb = (ushort_t*)(w + 71303168);     //  4.2MB, dead after postproc
    ushort_t* yb  = (ushort_t*)(w + 75497472);     // 16.8MB, dead after out-proj
    ushort_t* wq  = (ushort_t*)(w + 92274688);     //  8.4MB
    ushort_t* wk  = (ushort_t*)(w + 100663296);    //  2.1MB
    ushort_t* wv  = (ushort_t*)(w + 102760448);    //  2.1MB
    ushort_t* wo  = (ushort_t*)(w + 104857600);    //  8.4MB, dead after out-proj
    ushort_t* act = (ushort_t*)(w + 16777216);     // 67.1MB, aliases xm..yb (P5)
    ushort_t* wu  = (ushort_t*)(w + 83886080);     // 33.5MB, aliases yb-tail+wq..wo (P5)
    ushort_t* wd  = (ushort_t*)(w + 117440512);    // 33.5MB, ends 150994944
    ushort_t* m2  = (ushort_t*)(w + 0);            // aliases hb (P5)

    // weight conversions (wq..wo, wd regions are fresh; wu must wait for out-proj)
    f2bf_kernel<<<4096, 256, 0, stream>>>(q_w,    wq, 2048*2048/4);
    f2bf_kernel<<<1024, 256, 0, stream>>>(k_w,    wk,  512*2048/4);
    f2bf_kernel<<<1024, 256, 0, stream>>>(v_w,    wv,  512*2048/4);
    f2bf_kernel<<<4096, 256, 0, stream>>>(out_w,  wo, 2048*2048/4);
    f2bf_kernel<<<16384,256, 0, stream>>>(down_w, wd, 2048*8192/4);

    // 1. xm = mix(x,x0) fp32; h = rms(xm) bf16
    rms_kernel<true><<<N_, 256, 0, stream>>>(x, x0, resid_mix, xm, hb);
    // 2. projections (bf16 MFMA)
    gemm_bf16<0, ushort_t><<<dim3(16, 32), 256, 0, stream>>>(hb, wq, qb, D_, D_, nullptr, nullptr);
    gemm_bf16<0, ushort_t><<<dim3(4, 32), 256, 0, stream>>>(hb, wk, kb, KV_*HD_, D_, nullptr, nullptr);
    gemm_bf16<1, float><<<dim3(4, 32), 256, 0, stream>>>(hb, wv, out_vr, KV_*HD_, D_, v_embed, nullptr);
    // 3. v = l0*v0 + l1*v_resid  (bf16)
    vmix_kernel<<<(N_*KV_*HD_/4)/256, 256, 0, stream>>>(out_vr, v0, vr_lambda, vmb);
    // 4. per-head rms + rope (+gain)
    ropeqk_kernel<<<dim3(N_, H_ + KV_), 128, 0, stream>>>(qb, kb, q_gain);
    // 5. causal GQA attention -> yb (bf16)
    attn_kernel<<<dim3(S_/32, H_, B_), 256, 0, stream>>>(qb, kb, vmb, yb);
    // 6. v-hat projection + gate (in-place on yb)
    postproc_kernel<<<N_, 256, 0, stream>>>(hb, vmb, gate_w, gate_b, yb);
    // 7. c = xm + attn_scale * (yb @ out_w.T) -> out_c (fp32)
    gemm_bf16<2, float><<<dim3(16, 32), 256, 0, stream>>>(yb, wo, out_c, D_, D_, xm, attn_scale);
    // up_w conversion (region free only after out-proj)
    f2bf_kernel<<<16384, 256, 0, stream>>>(up_w, wu, 8192*2048/4);
    // 8. m2 = rms(c) bf16
    rms_kernel<false><<<N_, 256, 0, stream>>>(out_c, nullptr, nullptr, nullptr, m2);
    // 9. act = sqrelu(m2 @ up_w.T) bf16
    gemm_bf16<3, ushort_t><<<dim3(64, 32), 256, 0, stream>>>(m2, wu, act, MLP_, D_, nullptr, nullptr);
    // 10. c += mlp_scale * (act @ down_w.T)
    gemm_bf16<2, float><<<dim3(16, 32), 256, 0, stream>>>(act, wd, out_c, D_, MLP_, out_c, mlp_scale);
}

// Round 3
// 1079.215 us; speedup vs baseline: 7.2593x; 2.4188x over previous
//
#include <hip/hip_runtime.h>
#include <hip/hip_bf16.h>
#include <cfloat>

#define B_ 2
#define S_ 2048
#define D_ 2048
#define H_ 16
#define KV_ 4
#define HD_ 128
#define R_ 4
#define MLP_ 8192
#define N_ (B_*S_)

typedef unsigned short ushort_t;
typedef __bf16 bf16x8 __attribute__((ext_vector_type(8)));
typedef float f32x4 __attribute__((ext_vector_type(4)));

__device__ __forceinline__ float b2f(ushort_t u) {
    unsigned x = ((unsigned)u) << 16;
    return __builtin_bit_cast(float, x);
}
__device__ __forceinline__ ushort_t f2b(float f) {
    unsigned u = __builtin_bit_cast(unsigned, f);
    unsigned r = (u + 0x7fffu + ((u >> 16) & 1u)) >> 16;   // RNE
    return (ushort_t)r;
}

__device__ __forceinline__ void gload_lds16(const void* g, void* l) {
    __builtin_amdgcn_global_load_lds(
        (__attribute__((address_space(1))) void*)(g),
        (__attribute__((address_space(3))) void*)(l), 16, 0, 0);
}

// ---------------- fp32 -> bf16 conversion ----------------
__global__ __launch_bounds__(256) void f2bf_kernel(const float* __restrict__ in,
                                                   ushort_t* __restrict__ out, int n4)
{
    int i = blockIdx.x * 256 + threadIdx.x;
    if (i < n4) {
        float4 v = ((const float4*)in)[i];
        ushort4 o;
        o.x = f2b(v.x); o.y = f2b(v.y); o.z = f2b(v.z); o.w = f2b(v.w);
        ((ushort4*)out)[i] = o;
    }
}

// ---------------- mix + RMS -> bf16 h (optionally fp32 xm) ----------------
template<bool MIX>
__global__ __launch_bounds__(256) void rms_kernel(
    const float* __restrict__ x, const float* __restrict__ x0,
    const float* __restrict__ rm, float* __restrict__ xm_out,
    ushort_t* __restrict__ h_out)
{
    int n = blockIdx.x;
    int tid = threadIdx.x;
    const float4* xr = (const float4*)(x + (size_t)n * D_);
    float4 v[2];
    float ss = 0.f;
#pragma unroll
    for (int i = 0; i < 2; i++) {
        int c = tid + i * 256;
        float4 a = xr[c];
        if (MIX) {
            const float4* x0r = (const float4*)(x0 + (size_t)n * D_);
            const float4* rma = (const float4*)rm;
            const float4* rmb = (const float4*)(rm + D_);
            float4 b = x0r[c];
            float4 ra = rma[c], rb = rmb[c];
            a.x = ra.x*a.x + rb.x*b.x;
            a.y = ra.y*a.y + rb.y*b.y;
            a.z = ra.z*a.z + rb.z*b.z;
            a.w = ra.w*a.w + rb.w*b.w;
            ((float4*)(xm_out + (size_t)n * D_))[c] = a;
        }
        v[i] = a;
        ss += a.x*a.x + a.y*a.y + a.z*a.z + a.w*a.w;
    }
#pragma unroll
    for (int off = 32; off; off >>= 1) ss += __shfl_xor(ss, off);
    __shared__ float red[4];
    if ((tid & 63) == 0) red[tid >> 6] = ss;
    __syncthreads();
    float tot = red[0] + red[1] + red[2] + red[3];
    float r = rsqrtf(tot * (1.f / (float)D_) + FLT_EPSILON);
    ushort4* ho = (ushort4*)(h_out + (size_t)n * D_);
#pragma unroll
    for (int i = 0; i < 2; i++) {
        int c = tid + i * 256;
        float4 a = v[i];
        ushort4 o;
        o.x = f2b(a.x * r); o.y = f2b(a.y * r); o.z = f2b(a.z * r); o.w = f2b(a.w * r);
        ho[c] = o;
    }
}

// ---------------- bf16 MFMA GEMM: C[n,m] = sum_k A[n,k]*W[m,k] ----------------
template<int EPI, typename OutT>
__global__ __launch_bounds__(256) void gemm_bf16(
    const ushort_t* __restrict__ A, const ushort_t* __restrict__ W,
    OutT* __restrict__ C, int M, int Kd,
    const float* __restrict__ src, const float* __restrict__ svec)
{
    __shared__ ushort_t As[128 * 32];
    __shared__ ushort_t Bs[128 * 32];
    const int tid = threadIdx.x;
    const int wid = tid >> 6, lane = tid & 63;
    const int bn = blockIdx.y * 128;      // token rows
    const int bm = blockIdx.x * 128;      // feature cols
    const int wn = (wid >> 1) * 64;
    const int wm = (wid & 1) * 64;

    f32x4 acc[4][4] = {};

    const int lr = lane & 15;
    const int lk = (lane >> 4) * 16;      // byte offset
    const char* Ab = (const char*)As;
    const char* Bb = (const char*)Bs;
    const int ub0 = wid * 128;

#pragma unroll
    for (int p = 0; p < 2; p++) {
        int ub = ub0 + p * 64;
        int u = ub + lane;
        gload_lds16(A + (size_t)(bn + (u >> 2)) * Kd + (u & 3) * 8, (char*)As + ub * 16);
        gload_lds16(W + (size_t)(bm + (u >> 2)) * Kd + (u & 3) * 8, (char*)Bs + ub * 16);
    }
    __syncthreads();

    for (int k0 = 0;;) {
        bf16x8 af[4], bfr[4];
#pragma unroll
        for (int i = 0; i < 4; i++)
            af[i] = *(const bf16x8*)(Ab + (wn + i * 16 + lr) * 64 + lk);
#pragma unroll
        for (int j = 0; j < 4; j++)
            bfr[j] = *(const bf16x8*)(Bb + (wm + j * 16 + lr) * 64 + lk);
#pragma unroll
        for (int i = 0; i < 4; i++)
#pragma unroll
            for (int j = 0; j < 4; j++)
                acc[i][j] = __builtin_amdgcn_mfma_f32_16x16x32_bf16(af[i], bfr[j], acc[i][j], 0, 0, 0);

        k0 += 32;
        if (k0 >= Kd) break;
        __syncthreads();
#pragma unroll
        for (int p = 0; p < 2; p++) {
            int ub = ub0 + p * 64;
            int u = ub + lane;
            gload_lds16(A + (size_t)(bn + (u >> 2)) * Kd + k0 + (u & 3) * 8, (char*)As + ub * 16);
            gload_lds16(W + (size_t)(bm + (u >> 2)) * Kd + k0 + (u & 3) * 8, (char*)Bs + ub * 16);
        }
        __syncthreads();
    }

    const int cr = (lane >> 4) * 4;
    const int ccol = lane & 15;
#pragma unroll
    for (int i = 0; i < 4; i++) {
#pragma unroll
        for (int r = 0; r < 4; r++) {
            size_t rowoff = (size_t)(bn + wn + i * 16 + cr + r) * M;
#pragma unroll
            for (int j = 0; j < 4; j++) {
                int m = bm + wm + j * 16 + ccol;
                size_t off = rowoff + m;
                float v = acc[i][j][r];
                if (EPI == 1) v += src[off];
                else if (EPI == 2) v = src[off] + svec[m] * v;
                else if (EPI == 3) { float t = v >= 0.f ? v : 0.5f * v; v = t * t; }
                if constexpr (sizeof(OutT) == 2) C[off] = (OutT)f2b(v);
                else                             C[off] = v;
            }
        }
    }
}

// ---------------- v mixing: vm(bf16) = l0*v0 + l1*v_resid ----------------
__global__ __launch_bounds__(256) void vmix_kernel(
    const float* __restrict__ vres, const float* __restrict__ v0,
    const float* __restrict__ lam, ushort_t* __restrict__ vm)
{
    int i = blockIdx.x * 256 + threadIdx.x;
    float l0 = lam[0], l1 = lam[1];
    float4 a = ((const float4*)vres)[i];
    float4 b = ((const float4*)v0)[i];
    ushort4 o;
    o.x = f2b(l0*b.x + l1*a.x);
    o.y = f2b(l0*b.y + l1*a.y);
    o.z = f2b(l0*b.z + l1*a.z);
    o.w = f2b(l0*b.w + l1*a.w);
    ((ushort4*)vm)[i] = o;
}

// ---------------- vmb [b][s][512] -> vt [b*512 + c][s]  (bf16 transpose) ----------------
__global__ __launch_bounds__(256) void vtrans_kernel(const ushort_t* __restrict__ vm,
                                                     ushort_t* __restrict__ vt)
{
    int s = blockIdx.x * 64 + (threadIdx.x & 63);
    int c0 = blockIdx.y * 32 + (threadIdx.x >> 6) * 8;
    int b = blockIdx.z;
    uint4 raw = *(const uint4*)(vm + (size_t)(b * S_ + s) * (KV_*HD_) + c0);
    ushort_t tmp[8];
    *(uint4*)tmp = raw;
#pragma unroll
    for (int i = 0; i < 8; i++)
        vt[((size_t)b * (KV_*HD_) + c0 + i) * S_ + s] = tmp[i];
}

// ---------------- per-head RMS + RoPE (+q_gain), bf16 in/out ----------------
__global__ __launch_bounds__(128) void ropeqk_kernel(
    ushort_t* __restrict__ q, ushort_t* __restrict__ k,
    const float* __restrict__ q_gain)
{
    int n = blockIdx.x;
    int head = blockIdx.y;
    int tid = threadIdx.x;
    bool isq = head < H_;
    ushort_t* vec = isq ? (q + (size_t)n * D_ + head * HD_)
                        : (k + (size_t)n * (KV_*HD_) + (head - H_) * HD_);
    float v = b2f(vec[tid]);
    float ss = v * v;
#pragma unroll
    for (int off = 32; off; off >>= 1) ss += __shfl_xor(ss, off);
    __shared__ float red[2];
    __shared__ float sh[HD_];
    if ((tid & 63) == 0) red[tid >> 6] = ss;
    __syncthreads();
    float tot = red[0] + red[1];
    float r = rsqrtf(tot * (1.f / (float)HD_) + FLT_EPSILON);
    float xn = v * r;
    sh[tid] = xn;
    __syncthreads();
    int s = n & (S_ - 1);
    int i = (tid < 64) ? tid : tid - 64;
    const float L2B = 14.303585395422465f;  // log2(10000 * 2^(128/126))
    float invf = exp2f(-(float)i * (L2B / 64.f));
    float fr = (float)s * invf;
    float c = cosf(fr), sn = sinf(fr);
    float out;
    if (tid < 64) out =  xn * c + sh[tid + 64] * sn;
    else          out = -sh[tid - 64] * sn + xn * c;
    if (isq) out *= q_gain[head];
    vec[tid] = f2b(out);
}

// ---------------- MFMA flash attention (bf16 in/out, fp32 softmax/accum) ----------------
// grid (S/64, H, B); 4 waves/block, wave w owns Q rows [qb+w*16, qb+w*16+16).
// K staged as panels [kc][64 j][32], V^T staged as panels [jc][128 d][32].
__global__ __launch_bounds__(256) void attn_mfma_kernel(
    const ushort_t* __restrict__ Qg, const ushort_t* __restrict__ Kg,
    const ushort_t* __restrict__ Vtg, ushort_t* __restrict__ Y)
{
    const int b = blockIdx.z, h = blockIdx.y;
    const int kv = h >> 2;
    const int qb = blockIdx.x * 64;
    const int tid = threadIdx.x;
    const int wid = tid >> 6, lane = tid & 63;
    const int l15 = lane & 15, quad = lane >> 4;

    __shared__ ushort_t Ks[4 * 64 * 32];     // 16 KB
    __shared__ ushort_t Vs[2 * 128 * 32];    // 16 KB
    __shared__ ushort_t Ps[4][2 * 16 * 32];  // 8 KB (per-wave private)

    // Q fragments, held in registers for the whole kernel
    bf16x8 qf[4];
    {
        const ushort_t* qrow = Qg + (size_t)(b * S_ + qb + wid * 16 + l15) * D_ + h * HD_ + quad * 8;
#pragma unroll
        for (int kc = 0; kc < 4; kc++)
            qf[kc] = __builtin_bit_cast(bf16x8, *(const uint4*)(qrow + kc * 32));
    }

    f32x4 O[8];
    float m_r[4], l_r[4];
#pragma unroll
    for (int dt = 0; dt < 8; dt++)
#pragma unroll
        for (int r = 0; r < 4; r++) O[dt][r] = 0.f;
#pragma unroll
    for (int r = 0; r < 4; r++) { m_r[r] = -1e30f; l_r[r] = 0.f; }

    const size_t kgbase = (size_t)b * S_ * (KV_*HD_) + kv * HD_;
    const size_t vgbase = (size_t)(b * KV_ + kv) * HD_ * S_;
    const float CS = 0.12751743f;  // 1/sqrt(128) * log2(e)

    const int ntiles = blockIdx.x + 1;
    for (int t = 0; t < ntiles; t++) {
        const int k0 = t * 64;
        if (t) __syncthreads();
#pragma unroll
        for (int p = 0; p < 4; p++) {
            int ub = wid * 256 + p * 64 + lane;
            // K chunk: panel kc, row j, quad q
            int kc = ub >> 8, j = (ub >> 2) & 63, q = ub & 3;
            gload_lds16(Kg + kgbase + (size_t)(k0 + j) * (KV_*HD_) + kc * 32 + q * 8,
                        (char*)Ks + ub * 16);
            // Vt chunk: panel jc, row d, quad q
            int jc = ub >> 9, d = (ub >> 2) & 127;
            gload_lds16(Vtg + vgbase + (size_t)d * S_ + k0 + jc * 32 + q * 8,
                        (char*)Vs + ub * 16);
        }
        __syncthreads();

        // ---- S = Q K^T ----
        f32x4 sc[4];
#pragma unroll
        for (int jt = 0; jt < 4; jt++)
#pragma unroll
            for (int r = 0; r < 4; r++) sc[jt][r] = 0.f;
#pragma unroll
        for (int kc = 0; kc < 4; kc++) {
#pragma unroll
            for (int jt = 0; jt < 4; jt++) {
                bf16x8 kf = *(const bf16x8*)(Ks + kc * 2048 + (jt * 16 + l15) * 32 + quad * 8);
                sc[jt] = __builtin_amdgcn_mfma_f32_16x16x32_bf16(qf[kc], kf, sc[jt], 0, 0, 0);
            }
        }

        // ---- online softmax (C layout: col j = l15, row q = quad*4+r) ----
        float pv[4][4];
        const bool diag = (t == ntiles - 1);
#pragma unroll
        for (int jt = 0; jt < 4; jt++)
#pragma unroll
            for (int r = 0; r < 4; r++) {
                float s = sc[jt][r] * CS;
                if (diag && (jt * 16 + l15 > wid * 16 + quad * 4 + r)) s = -1e30f;
                pv[jt][r] = s;
            }
        float al[4];
#pragma unroll
        for (int r = 0; r < 4; r++) {
            float m0 = fmaxf(fmaxf(pv[0][r], pv[1][r]), fmaxf(pv[2][r], pv[3][r]));
#pragma unroll
            for (int o = 1; o < 16; o <<= 1) m0 = fmaxf(m0, __shfl_xor(m0, o));
            float mn = fmaxf(m_r[r], m0);
            al[r] = exp2f(m_r[r] - mn);
            m_r[r] = mn;
            float srow = 0.f;
#pragma unroll
            for (int jt = 0; jt < 4; jt++) { pv[jt][r] = exp2f(pv[jt][r] - mn); srow += pv[jt][r]; }
#pragma unroll
            for (int o = 1; o < 16; o <<= 1) srow += __shfl_xor(srow, o);
            l_r[r] = l_r[r] * al[r] + srow;
        }
#pragma unroll
        for (int dt = 0; dt < 8; dt++)
#pragma unroll
            for (int r = 0; r < 4; r++) O[dt][r] *= al[r];

        // ---- P: C layout -> A layout via per-wave LDS ----
        ushort_t* pw = Ps[wid];
#pragma unroll
        for (int jt = 0; jt < 4; jt++)
#pragma unroll
            for (int r = 0; r < 4; r++)
                pw[(jt >> 1) * 512 + (quad * 4 + r) * 32 + (jt & 1) * 16 + l15] = f2b(pv[jt][r]);

        // ---- O += P V ----
#pragma unroll
        for (int jc = 0; jc < 2; jc++) {
            bf16x8 pf = *(const bf16x8*)(pw + jc * 512 + l15 * 32 + quad * 8);
#pragma unroll
            for (int dt = 0; dt < 8; dt++) {
                bf16x8 vf = *(const bf16x8*)(Vs + jc * 4096 + (dt * 16 + l15) * 32 + quad * 8);
                O[dt] = __builtin_amdgcn_mfma_f32_16x16x32_bf16(pf, vf, O[dt], 0, 0, 0);
            }
        }
    }

    // epilogue
#pragma unroll
    for (int r = 0; r < 4; r++) {
        float inv = 1.f / l_r[r];
        size_t row = (size_t)(b * S_ + qb + wid * 16 + quad * 4 + r) * D_ + h * HD_;
#pragma unroll
        for (int dt = 0; dt < 8; dt++)
            Y[row + dt * 16 + l15] = f2b(O[dt][r] * inv);
    }
}

// ---------------- v-hat projection + sigmoid gate (bf16 y in-place) ----------------
__global__ __launch_bounds__(256) void postproc_kernel(
    const ushort_t* __restrict__ h, const ushort_t* __restrict__ vmix,
    const float* __restrict__ gw, const float* __restrict__ gb,
    ushort_t* __restrict__ y)
{
    int n = blockIdx.x;
    int tid = threadIdx.x;
    int wave = tid >> 6, lane = tid & 63;
    const ushort_t* hrow = h + (size_t)n * D_;
    float acc[4] = {0.f, 0.f, 0.f, 0.f};
    for (int d = lane; d < D_; d += 64) {
        float hv = b2f(hrow[d]);
#pragma unroll
        for (int r = 0; r < 4; r++)
            acc[r] += hv * gw[(size_t)(wave*4 + r) * D_ + d];
    }
#pragma unroll
    for (int off = 32; off; off >>= 1)
#pragma unroll
        for (int r = 0; r < 4; r++) acc[r] += __shfl_xor(acc[r], off);
    float gate[4];
#pragma unroll
    for (int r = 0; r < 4; r++)
        gate[r] = 1.f / (1.f + __expf(-(acc[r] + gb[wave*4 + r])));
    const ushort_t* vrow = vmix + (size_t)n * (KV_*HD_) + wave * HD_;
    float v0 = b2f(vrow[lane]), v1 = b2f(vrow[lane + 64]);
    float ss = v0*v0 + v1*v1;
#pragma unroll
    for (int off = 32; off; off >>= 1) ss += __shfl_xor(ss, off);
    float nrm = fmaxf(sqrtf(ss), 1e-12f);
    float vh0 = v0 / nrm, vh1 = v1 / nrm;
    ushort_t* yrow = y + (size_t)n * D_ + wave * (R_ * HD_);
#pragma unroll
    for (int r = 0; r < 4; r++) {
        float y0 = b2f(yrow[r*HD_ + lane]), y1 = b2f(yrow[r*HD_ + lane + 64]);
        float dot = y0*vh0 + y1*vh1;
#pragma unroll
        for (int off = 32; off; off >>= 1) dot += __shfl_xor(dot, off);
        yrow[r*HD_ + lane]      = f2b((y0 - dot*vh0) * gate[r]);
        yrow[r*HD_ + lane + 64] = f2b((y1 - dot*vh1) * gate[r]);
    }
}

extern "C" void kernel_launch(void* const* d_in, const int* in_sizes, int n_in,
                              void* d_out, int out_size, void* d_ws, size_t ws_size,
                              hipStream_t stream) {
    const float* x          = (const float*)d_in[0];
    const float* x0         = (const float*)d_in[1];
    const float* q_w        = (const float*)d_in[2];
    const float* k_w        = (const float*)d_in[3];
    const float* v_w        = (const float*)d_in[4];
    const float* out_w      = (const float*)d_in[5];
    const float* up_w       = (const float*)d_in[6];
    const float* down_w     = (const float*)d_in[7];
    const float* v_embed    = (const float*)d_in[8];
    const float* v0         = (const float*)d_in[9];
    const float* q_gain     = (const float*)d_in[10];
    const float* gate_w     = (const float*)d_in[11];
    const float* gate_b     = (const float*)d_in[12];
    const float* vr_lambda  = (const float*)d_in[13];
    const float* attn_scale = (const float*)d_in[14];
    const float* mlp_scale  = (const float*)d_in[15];
    const float* resid_mix  = (const float*)d_in[16];

    float* out_c  = (float*)d_out;
    float* out_vr = out_c + (size_t)N_ * D_;

    // phase-aliased workspace (peak 151.0 MB, proven available in R2)
    char* w = (char*)d_ws;
    ushort_t* hb  = (ushort_t*)(w + 0);            // 16.8MB
    float*    xm  = (float*)   (w + 16777216);     // 33.5MB
    ushort_t* qb  = (ushort_t*)(w + 50331648);     // 16.8MB
    ushort_t* kb  = (ushort_t*)(w + 67108864);     //  4.2MB
    ushort_t* vmb = (ushort_t*)(w + 71303168);     //  4.2MB
    ushort_t* yb  = (ushort_t*)(w + 75497472);     // 16.8MB
    ushort_t* wq  = (ushort_t*)(w + 92274688);     //  8.4MB
    ushort_t* wk  = (ushort_t*)(w + 100663296);    //  2.1MB
    ushort_t* wv  = (ushort_t*)(w + 102760448);    //  2.1MB
    ushort_t* wo  = (ushort_t*)(w + 104857600);    //  8.4MB
    ushort_t* vtb = (ushort_t*)(w + 113246208);    //  4.2MB (hole before wd)
    ushort_t* act = (ushort_t*)(w + 16777216);     // 67.1MB (aliases xm..yb, MLP phase)
    ushort_t* wu  = (ushort_t*)(w + 83886080);     // 33.5MB (aliases yb tail + wq..wo)
    ushort_t* wd  = (ushort_t*)(w + 117440512);    // 33.5MB, ends 150994944
    ushort_t* m2  = (ushort_t*)(w + 0);            // aliases hb (MLP phase)

    f2bf_kernel<<<4096, 256, 0, stream>>>(q_w,    wq, 2048*2048/4);
    f2bf_kernel<<<1024, 256, 0, stream>>>(k_w,    wk,  512*2048/4);
    f2bf_kernel<<<1024, 256, 0, stream>>>(v_w,    wv,  512*2048/4);
    f2bf_kernel<<<4096, 256, 0, stream>>>(out_w,  wo, 2048*2048/4);
    f2bf_kernel<<<16384,256, 0, stream>>>(down_w, wd, 2048*8192/4);

    // 1. xm = mix(x,x0) fp32; h = rms(xm) bf16
    rms_kernel<true><<<N_, 256, 0, stream>>>(x, x0, resid_mix, xm, hb);
    // 2. projections
    gemm_bf16<0, ushort_t><<<dim3(16, 32), 256, 0, stream>>>(hb, wq, qb, D_, D_, nullptr, nullptr);
    gemm_bf16<0, ushort_t><<<dim3(4, 32), 256, 0, stream>>>(hb, wk, kb, KV_*HD_, D_, nullptr, nullptr);
    gemm_bf16<1, float><<<dim3(4, 32), 256, 0, stream>>>(hb, wv, out_vr, KV_*HD_, D_, v_embed, nullptr);
    // 3. v = l0*v0 + l1*v_resid (bf16) + transposed copy for attention
    vmix_kernel<<<(N_*KV_*HD_/4)/256, 256, 0, stream>>>(out_vr, v0, vr_lambda, vmb);
    vtrans_kernel<<<dim3(S_/64, (KV_*HD_)/32, B_), 256, 0, stream>>>(vmb, vtb);
    // 4. per-head rms + rope (+gain)
    ropeqk_kernel<<<dim3(N_, H_ + KV_), 128, 0, stream>>>(qb, kb, q_gain);
    // 5. causal GQA attention (MFMA flash) -> yb
    attn_mfma_kernel<<<dim3(S_/64, H_, B_), 256, 0, stream>>>(qb, kb, vtb, yb);
    // 6. v-hat projection + gate (in-place on yb)
    postproc_kernel<<<N_, 256, 0, stream>>>(hb, vmb, gate_w, gate_b, yb);
    // 7. c = xm + attn_scale * (yb @ out_w.T) -> out_c
    gemm_bf16<2, float><<<dim3(16, 32), 256, 0, stream>>>(yb, wo, out_c, D_, D_, xm, attn_scale);
    f2bf_kernel<<<16384, 256, 0, stream>>>(up_w, wu, 8192*2048/4);
    // 8. m2 = rms(c) bf16
    rms_kernel<false><<<N_, 256, 0, stream>>>(out_c, nullptr, nullptr, nullptr, m2);
    // 9. act = sqrelu(m2 @ up_w.T)
    gemm_bf16<3, ushort_t><<<dim3(64, 32), 256, 0, stream>>>(m2, wu, act, MLP_, D_, nullptr, nullptr);
    // 10. c += mlp_scale * (act @ down_w.T)
    gemm_bf16<2, float><<<dim3(16, 32), 256, 0, stream>>>(act, wd, out_c, D_, MLP_, out_c, mlp_scale);
}